// Round 8
// baseline (104.835 us; speedup 1.0000x reference)
//
#include <hip/hip_runtime.h>

constexpr int U_ = 256;
constexpr int I_ = 512;
constexpr int J_ = 31;
constexpr int UI = U_ * I_;               // 131072 pairs
constexpr size_t D_BYTES = (size_t)UI * 20 * 4;   // 10.5 MB workspace for D

// ---------------- Phase 1: async-LDS-staged descriptor build -----------------
// Block = 128 threads = 32 pairs x 4 lanes. Stage Sg (32*93 f) + R (32*124 f)
// = 27776 B into LDS via global_load_lds (zero VGPR cost, async), one barrier,
// then the l-split compute (lane g owns R-component g) reading from LDS.
// Sg reads: 4-lane broadcast, 16 distinct banks -> conflict-free.
// R reads: 2-way bank alias -> free (m136).
constexpr int PPB       = 32;                  // pairs per block
constexpr int THR       = 128;                 // threads per block
constexpr int SG_BYTES  = PPB * 93 * 4;        // 11904
constexpr int R_BYTES   = PPB * 124 * 4;       // 15872
constexpr int TOT_BYTES = SG_BYTES + R_BYTES;  // 27776
constexpr int FULL_RNDS = TOT_BYTES / 1024;    // 27 full 1KB wave-rounds
constexpr int TAIL_F4   = (TOT_BYTES - FULL_RNDS * 1024) / 16;   // 8

typedef __attribute__((address_space(1))) const void g1void;
typedef __attribute__((address_space(3))) void s3void;

__global__ __launch_bounds__(THR) void dqn_phase1(
    const float* __restrict__ Sg, const float* __restrict__ R,
    const float* __restrict__ W1, const float* __restrict__ b1,
    const float* __restrict__ W2, const float* __restrict__ b2,
    float* __restrict__ Dws)
{
    __shared__ float4 buf4[TOT_BYTES / 16];
    char* buf = reinterpret_cast<char*>(buf4);

    const int tid  = threadIdx.x;
    const int wave = tid >> 6;
    const int lane = tid & 63;

    const char* gS = reinterpret_cast<const char*>(Sg) + (size_t)blockIdx.x * SG_BYTES;
    const char* gR = reinterpret_cast<const char*>(R)  + (size_t)blockIdx.x * R_BYTES;

    // Async DMA: each wave-round moves 1 KB (lane i -> base + i*16, linear).
    #pragma unroll
    for (int r = wave; r < FULL_RNDS; r += 2) {
        int byte = r * 1024 + lane * 16;
        const void* gsrc = (byte < SG_BYTES)
                         ? (const void*)(gS + byte)
                         : (const void*)(gR + (byte - SG_BYTES));
        __builtin_amdgcn_global_load_lds((g1void*)gsrc,
                                         (s3void*)(buf + r * 1024),
                                         16, 0, 0);
    }
    // 128-byte tail (pure-R region) via plain copy, 8 lanes.
    if (tid < TAIL_F4) {
        const float4* s = reinterpret_cast<const float4*>(gR + (FULL_RNDS * 1024 - SG_BYTES));
        buf4[FULL_RNDS * 64 + tid] = s[tid];
    }
    __syncthreads();   // compiler drains vmcnt(0) before s_barrier -> DMA done

    // ---- compute: lane g of local pair lp (v5's proven l-split) ----
    const int lp   = tid >> 2;        // 0..31
    const int g    = tid & 3;
    const int pair = blockIdx.x * PPB + lp;

    const float* bufF = reinterpret_cast<const float*>(buf4);
    const float* sgL  = bufF + lp * 93;
    const float* rL   = bufF + (SG_BYTES / 4) + lp * 124 + g;

    // Uniform weights -> SGPRs (compiler scalarizes)
    float w10[10], w11[10], w12[10], c1w[10];
    #pragma unroll
    for (int p = 0; p < 10; ++p) {
        w10[p] = W1[p]; w11[p] = W1[10 + p]; w12[p] = W1[20 + p]; c1w[p] = b1[p];
    }

    float M[10];
    float Rsg = 0.f;
    #pragma unroll
    for (int p = 0; p < 10; ++p) M[p] = 0.f;

    #pragma unroll
    for (int j = 0; j < J_; ++j) {
        float a0 = sgL[j * 3 + 0];     // broadcast across the 4 lanes
        float a1 = sgL[j * 3 + 1];
        float a2 = sgL[j * 3 + 2];
        float r  = rL[j * 4];          // lane-private component
        #pragma unroll
        for (int p = 0; p < 10; ++p) {
            float t = c1w[p] + a0 * w10[p] + a1 * w11[p] + a2 * w12[p];
            t = t > 0.f ? t : 0.f;     // ReLU
            M[p] += r * t;
        }
        Rsg += r;
    }

    // T2 row g: T2g[n] = sum_p M[p]*W2[p][n] + Rsg*b2[n]
    float T2g[10];
    #pragma unroll
    for (int n = 0; n < 10; ++n) T2g[n] = Rsg * b2[n];
    #pragma unroll
    for (int p = 0; p < 10; ++p) {
        float m = M[p];
        #pragma unroll
        for (int n = 0; n < 10; ++n) T2g[n] += m * W2[p * 10 + n];
    }

    // D[k*10+n] = sum over 4 lanes of T2g[k]*T2g[n]  (T1 == T2^T)
    float D[20];
    #pragma unroll
    for (int k = 0; k < 2; ++k)
        #pragma unroll
        for (int n = 0; n < 10; ++n) D[k * 10 + n] = T2g[k] * T2g[n];
    #pragma unroll
    for (int t = 0; t < 20; ++t) {
        D[t] += __shfl_xor(D[t], 1);
        D[t] += __shfl_xor(D[t], 2);
    }

    // Transposed store, static register indices per g-branch (no scratch).
    float* dw = Dws + pair;
    if (g == 0) {
        dw[0 * UI] = D[0];  dw[1 * UI] = D[1];  dw[2 * UI] = D[2];
        dw[3 * UI] = D[3];  dw[4 * UI] = D[4];
    } else if (g == 1) {
        dw[5 * UI] = D[5];  dw[6 * UI] = D[6];  dw[7 * UI] = D[7];
        dw[8 * UI] = D[8];  dw[9 * UI] = D[9];
    } else if (g == 2) {
        dw[10 * UI] = D[10]; dw[11 * UI] = D[11]; dw[12 * UI] = D[12];
        dw[13 * UI] = D[13]; dw[14 * UI] = D[14];
    } else {
        dw[15 * UI] = D[15]; dw[16 * UI] = D[16]; dw[17 * UI] = D[17];
        dw[18 * UI] = D[18]; dw[19 * UI] = D[19];
    }
}

// ---------------- Phase 2: fit MLP 20->32->32->1 (1 thread/pair) -------------
__global__ __launch_bounds__(256) void dqn_phase2(
    const float* __restrict__ Dws,
    const float* __restrict__ Wf1, const float* __restrict__ bf1,
    const float* __restrict__ Wf2, const float* __restrict__ bf2,
    const float* __restrict__ Wf3, const float* __restrict__ bf3,
    float* __restrict__ out)
{
    const int pair = blockIdx.x * 256 + threadIdx.x;

    float D[20];
    #pragma unroll
    for (int t = 0; t < 20; ++t) D[t] = Dws[(size_t)t * UI + pair];   // coalesced

    float f1[32];
    #pragma unroll
    for (int o = 0; o < 32; ++o) f1[o] = bf1[o];
    #pragma unroll
    for (int kk = 0; kk < 20; ++kk) {
        const float4* wrow = reinterpret_cast<const float4*>(Wf1 + kk * 32);
        float d = D[kk];
        #pragma unroll
        for (int v = 0; v < 8; ++v) {
            float4 w = wrow[v];
            f1[4 * v + 0] += d * w.x;
            f1[4 * v + 1] += d * w.y;
            f1[4 * v + 2] += d * w.z;
            f1[4 * v + 3] += d * w.w;
        }
    }
    #pragma unroll
    for (int o = 0; o < 32; ++o) f1[o] = f1[o] > 0.f ? f1[o] : 0.f;

    float f2[32];
    #pragma unroll
    for (int o = 0; o < 32; ++o) f2[o] = bf2[o];
    #pragma unroll
    for (int kk = 0; kk < 32; ++kk) {
        const float4* wrow = reinterpret_cast<const float4*>(Wf2 + kk * 32);
        float d = f1[kk];
        #pragma unroll
        for (int v = 0; v < 8; ++v) {
            float4 w = wrow[v];
            f2[4 * v + 0] += d * w.x;
            f2[4 * v + 1] += d * w.y;
            f2[4 * v + 2] += d * w.z;
            f2[4 * v + 3] += d * w.w;
        }
    }
    #pragma unroll
    for (int o = 0; o < 32; ++o) f2[o] = f2[o] > 0.f ? f2[o] : 0.f;

    float q = bf3[0];
    #pragma unroll
    for (int o = 0; o < 32; o += 4) {
        float4 w = *reinterpret_cast<const float4*>(Wf3 + o);
        q += f2[o + 0] * w.x + f2[o + 1] * w.y + f2[o + 2] * w.z + f2[o + 3] * w.w;
    }

    out[pair] = q;
}

// ---------------- Fallback: known-good fused v1 (if ws too small) ------------
struct Nb1 { float s0, s1, s2; float4 r; };
__device__ __forceinline__ Nb1 load_nb1(const float* __restrict__ sg,
                                        const float* __restrict__ rr, int j) {
    Nb1 d;
    d.s0 = sg[j * 3 + 0]; d.s1 = sg[j * 3 + 1]; d.s2 = sg[j * 3 + 2];
    d.r = *reinterpret_cast<const float4*>(rr + j * 4);
    return d;
}
__global__ __launch_bounds__(256, 2) void dqn_fused_fb(
    const float* __restrict__ Sg,  const float* __restrict__ R,
    const float* __restrict__ W1,  const float* __restrict__ b1,
    const float* __restrict__ W2,  const float* __restrict__ b2,
    const float* __restrict__ Wf1, const float* __restrict__ bf1,
    const float* __restrict__ Wf2, const float* __restrict__ bf2,
    const float* __restrict__ Wf3, const float* __restrict__ bf3,
    float* __restrict__ out)
{
    const int pair = blockIdx.x * 256 + threadIdx.x;
    const float* sg = Sg + (size_t)pair * (J_ * 3);
    const float* rr = R  + (size_t)pair * (J_ * 4);
    float w1[3][10], c1[10];
    #pragma unroll
    for (int k = 0; k < 3; ++k)
        #pragma unroll
        for (int p = 0; p < 10; ++p) w1[k][p] = W1[k * 10 + p];
    #pragma unroll
    for (int p = 0; p < 10; ++p) c1[p] = b1[p];
    float M[4][10]; float Rs[4] = {0.f,0.f,0.f,0.f};
    #pragma unroll
    for (int l = 0; l < 4; ++l)
        #pragma unroll
        for (int p = 0; p < 10; ++p) M[l][p] = 0.f;
    #pragma unroll 1
    for (int j = 0; j < J_; ++j) {
        Nb1 nb = load_nb1(sg, rr, j);
        float h[10];
        #pragma unroll
        for (int p = 0; p < 10; ++p) {
            float t = c1[p] + nb.s0*w1[0][p] + nb.s1*w1[1][p] + nb.s2*w1[2][p];
            h[p] = t > 0.f ? t : 0.f;
        }
        Rs[0]+=nb.r.x; Rs[1]+=nb.r.y; Rs[2]+=nb.r.z; Rs[3]+=nb.r.w;
        #pragma unroll
        for (int p = 0; p < 10; ++p) {
            M[0][p]+=nb.r.x*h[p]; M[1][p]+=nb.r.y*h[p];
            M[2][p]+=nb.r.z*h[p]; M[3][p]+=nb.r.w*h[p];
        }
    }
    float T2[4][10];
    #pragma unroll
    for (int l = 0; l < 4; ++l)
        #pragma unroll
        for (int n = 0; n < 10; ++n) T2[l][n] = Rs[l] * b2[n];
    #pragma unroll
    for (int p = 0; p < 10; ++p) {
        #pragma unroll
        for (int l = 0; l < 4; ++l) {
            float m = M[l][p];
            #pragma unroll
            for (int n = 0; n < 10; ++n) T2[l][n] += m * W2[p * 10 + n];
        }
    }
    float D[20];
    #pragma unroll
    for (int k = 0; k < 2; ++k)
        #pragma unroll
        for (int n = 0; n < 10; ++n)
            D[k*10+n] = T2[0][k]*T2[0][n] + T2[1][k]*T2[1][n]
                      + T2[2][k]*T2[2][n] + T2[3][k]*T2[3][n];
    float f1[32];
    #pragma unroll
    for (int o = 0; o < 32; ++o) f1[o] = bf1[o];
    #pragma unroll
    for (int kk = 0; kk < 20; ++kk) {
        const float4* wrow = reinterpret_cast<const float4*>(Wf1 + kk * 32);
        float d = D[kk];
        #pragma unroll
        for (int v = 0; v < 8; ++v) {
            float4 w = wrow[v];
            f1[4*v+0]+=d*w.x; f1[4*v+1]+=d*w.y; f1[4*v+2]+=d*w.z; f1[4*v+3]+=d*w.w;
        }
    }
    #pragma unroll
    for (int o = 0; o < 32; ++o) f1[o] = f1[o] > 0.f ? f1[o] : 0.f;
    float f2[32];
    #pragma unroll
    for (int o = 0; o < 32; ++o) f2[o] = bf2[o];
    #pragma unroll
    for (int kk = 0; kk < 32; ++kk) {
        const float4* wrow = reinterpret_cast<const float4*>(Wf2 + kk * 32);
        float d = f1[kk];
        #pragma unroll
        for (int v = 0; v < 8; ++v) {
            float4 w = wrow[v];
            f2[4*v+0]+=d*w.x; f2[4*v+1]+=d*w.y; f2[4*v+2]+=d*w.z; f2[4*v+3]+=d*w.w;
        }
    }
    #pragma unroll
    for (int o = 0; o < 32; ++o) f2[o] = f2[o] > 0.f ? f2[o] : 0.f;
    float q = bf3[0];
    #pragma unroll
    for (int o = 0; o < 32; o += 4) {
        float4 w = *reinterpret_cast<const float4*>(Wf3 + o);
        q += f2[o+0]*w.x + f2[o+1]*w.y + f2[o+2]*w.z + f2[o+3]*w.w;
    }
    out[pair] = q;
}

extern "C" void kernel_launch(void* const* d_in, const int* in_sizes, int n_in,
                              void* d_out, int out_size, void* d_ws, size_t ws_size,
                              hipStream_t stream) {
    const float* Sg  = (const float*)d_in[0];
    const float* R   = (const float*)d_in[1];
    const float* W1  = (const float*)d_in[2];
    const float* b1  = (const float*)d_in[3];
    const float* W2  = (const float*)d_in[4];
    const float* b2  = (const float*)d_in[5];
    const float* Wf1 = (const float*)d_in[6];
    const float* bf1 = (const float*)d_in[7];
    const float* Wf2 = (const float*)d_in[8];
    const float* bf2 = (const float*)d_in[9];
    const float* Wf3 = (const float*)d_in[10];
    const float* bf3 = (const float*)d_in[11];
    float* out = (float*)d_out;

    if (ws_size >= D_BYTES) {
        float* Dws = (float*)d_ws;
        dqn_phase1<<<dim3(UI / PPB), dim3(THR), 0, stream>>>(
            Sg, R, W1, b1, W2, b2, Dws);
        dqn_phase2<<<dim3(UI / 256), dim3(256), 0, stream>>>(
            Dws, Wf1, bf1, Wf2, bf2, Wf3, bf3, out);
    } else {
        dqn_fused_fb<<<dim3(UI / 256), dim3(256), 0, stream>>>(
            Sg, R, W1, b1, W2, b2, Wf1, bf1, Wf2, bf2, Wf3, bf3, out);
    }
}

// Round 9
// 74.143 us; speedup vs baseline: 1.4140x; 1.4140x over previous
//
#include <hip/hip_runtime.h>

constexpr int U_ = 256;
constexpr int I_ = 512;
constexpr int J_ = 31;
constexpr int UI = U_ * I_;               // 131072 pairs
constexpr size_t D_BYTES = (size_t)UI * 20 * 4;   // 10.5 MB workspace for D

// ---------------- Phase 1: async-LDS-staged descriptor build -----------------
// Block = 64 threads (1 wave) = 16 pairs x 4 lanes. Stage Sg (16*93 f) +
// R (16*124 f) = 13888 B into LDS via global_load_lds (zero VGPR), barrier,
// then l-split compute (lane g owns R-component g) with a ROLLED j-loop
// (depth-2 LDS prefetch) to keep VGPR low. 11 blocks/CU co-resident: one
// block's staging overlaps other blocks' compute.
constexpr int PPB       = 16;                  // pairs per block
constexpr int THR       = 64;                  // threads per block (1 wave)
constexpr int SG_BYTES  = PPB * 93 * 4;        // 5952
constexpr int R_BYTES   = PPB * 124 * 4;       // 7936
constexpr int TOT_BYTES = SG_BYTES + R_BYTES;  // 13888
constexpr int FULL_RNDS = TOT_BYTES / 1024;    // 13 full 1KB wave-rounds
constexpr int TAIL_F4   = (TOT_BYTES - FULL_RNDS * 1024) / 16;   // 36

typedef __attribute__((address_space(1))) const void g1void;
typedef __attribute__((address_space(3))) void s3void;

__global__ __launch_bounds__(THR) void dqn_phase1(
    const float* __restrict__ Sg, const float* __restrict__ R,
    const float* __restrict__ W1, const float* __restrict__ b1,
    const float* __restrict__ W2, const float* __restrict__ b2,
    float* __restrict__ Dws)
{
    __shared__ float4 buf4[TOT_BYTES / 16];
    char* buf = reinterpret_cast<char*>(buf4);

    const int tid = threadIdx.x;   // == lane (single wave)

    const char* gS = reinterpret_cast<const char*>(Sg) + (size_t)blockIdx.x * SG_BYTES;
    const char* gR = reinterpret_cast<const char*>(R)  + (size_t)blockIdx.x * R_BYTES;

    // Async DMA: each round moves 1 KB (HW writes lds_base + lane*16, linear).
    #pragma unroll
    for (int r = 0; r < FULL_RNDS; ++r) {
        int byte = r * 1024 + tid * 16;
        const void* gsrc = (byte < SG_BYTES)
                         ? (const void*)(gS + byte)
                         : (const void*)(gR + (byte - SG_BYTES));
        __builtin_amdgcn_global_load_lds((g1void*)gsrc,
                                         (s3void*)(buf + r * 1024),
                                         16, 0, 0);
    }
    // 576-byte tail (pure-R region) via plain copy, 36 lanes.
    if (tid < TAIL_F4) {
        const float4* s = reinterpret_cast<const float4*>(
            gR + (FULL_RNDS * 1024 - SG_BYTES));
        buf4[FULL_RNDS * 64 + tid] = s[tid];
    }
    __syncthreads();   // drains vmcnt(0) -> DMA complete

    // ---- compute: lane g of local pair lp (l-split) ----
    const int lp   = tid >> 2;        // 0..15
    const int g    = tid & 3;
    const int pair = blockIdx.x * PPB + lp;

    const float* bufF = reinterpret_cast<const float*>(buf4);
    const float* sgL  = bufF + lp * 93;                       // 4-lane broadcast
    const float* rL   = bufF + (SG_BYTES / 4) + lp * 124 + g; // 2-way alias: free

    // Uniform weights -> SGPRs (compiler scalarizes)
    float w10[10], w11[10], w12[10], c1w[10];
    #pragma unroll
    for (int p = 0; p < 10; ++p) {
        w10[p] = W1[p]; w11[p] = W1[10 + p]; w12[p] = W1[20 + p]; c1w[p] = b1[p];
    }

    float M[10];
    float Rsg = 0.f;
    #pragma unroll
    for (int p = 0; p < 10; ++p) M[p] = 0.f;

    // Rolled j-loop, depth-2 LDS prefetch: ~8 live staged values, low VGPR.
    float a0 = sgL[0], a1 = sgL[1], a2 = sgL[2], rv = rL[0];
    #pragma unroll 1
    for (int j = 0; j < J_ - 1; ++j) {
        float n0 = sgL[j * 3 + 3];
        float n1 = sgL[j * 3 + 4];
        float n2 = sgL[j * 3 + 5];
        float nr = rL[j * 4 + 4];
        #pragma unroll
        for (int p = 0; p < 10; ++p) {
            float t = c1w[p] + a0 * w10[p] + a1 * w11[p] + a2 * w12[p];
            t = t > 0.f ? t : 0.f;     // ReLU
            M[p] += rv * t;
        }
        Rsg += rv;
        a0 = n0; a1 = n1; a2 = n2; rv = nr;
    }
    #pragma unroll
    for (int p = 0; p < 10; ++p) {
        float t = c1w[p] + a0 * w10[p] + a1 * w11[p] + a2 * w12[p];
        t = t > 0.f ? t : 0.f;
        M[p] += rv * t;
    }
    Rsg += rv;

    // T2 row g: T2g[n] = sum_p M[p]*W2[p][n] + Rsg*b2[n]
    float T2g[10];
    #pragma unroll
    for (int n = 0; n < 10; ++n) T2g[n] = Rsg * b2[n];
    #pragma unroll
    for (int p = 0; p < 10; ++p) {
        float m = M[p];
        #pragma unroll
        for (int n = 0; n < 10; ++n) T2g[n] += m * W2[p * 10 + n];
    }

    // D[k*10+n] = sum over 4 lanes of T2g[k]*T2g[n]  (T1 == T2^T)
    float D[20];
    #pragma unroll
    for (int k = 0; k < 2; ++k)
        #pragma unroll
        for (int n = 0; n < 10; ++n) D[k * 10 + n] = T2g[k] * T2g[n];
    #pragma unroll
    for (int t = 0; t < 20; ++t) {
        D[t] += __shfl_xor(D[t], 1);
        D[t] += __shfl_xor(D[t], 2);
    }

    // Transposed store, static register indices per g-branch (no scratch).
    float* dw = Dws + pair;
    if (g == 0) {
        dw[0 * UI] = D[0];  dw[1 * UI] = D[1];  dw[2 * UI] = D[2];
        dw[3 * UI] = D[3];  dw[4 * UI] = D[4];
    } else if (g == 1) {
        dw[5 * UI] = D[5];  dw[6 * UI] = D[6];  dw[7 * UI] = D[7];
        dw[8 * UI] = D[8];  dw[9 * UI] = D[9];
    } else if (g == 2) {
        dw[10 * UI] = D[10]; dw[11 * UI] = D[11]; dw[12 * UI] = D[12];
        dw[13 * UI] = D[13]; dw[14 * UI] = D[14];
    } else {
        dw[15 * UI] = D[15]; dw[16 * UI] = D[16]; dw[17 * UI] = D[17];
        dw[18 * UI] = D[18]; dw[19 * UI] = D[19];
    }
}

// ---------------- Phase 2: fit MLP 20->32->32->1 (1 thread/pair) -------------
__global__ __launch_bounds__(256) void dqn_phase2(
    const float* __restrict__ Dws,
    const float* __restrict__ Wf1, const float* __restrict__ bf1,
    const float* __restrict__ Wf2, const float* __restrict__ bf2,
    const float* __restrict__ Wf3, const float* __restrict__ bf3,
    float* __restrict__ out)
{
    const int pair = blockIdx.x * 256 + threadIdx.x;

    float D[20];
    #pragma unroll
    for (int t = 0; t < 20; ++t) D[t] = Dws[(size_t)t * UI + pair];   // coalesced

    float f1[32];
    #pragma unroll
    for (int o = 0; o < 32; ++o) f1[o] = bf1[o];
    #pragma unroll
    for (int kk = 0; kk < 20; ++kk) {
        const float4* wrow = reinterpret_cast<const float4*>(Wf1 + kk * 32);
        float d = D[kk];
        #pragma unroll
        for (int v = 0; v < 8; ++v) {
            float4 w = wrow[v];
            f1[4 * v + 0] += d * w.x;
            f1[4 * v + 1] += d * w.y;
            f1[4 * v + 2] += d * w.z;
            f1[4 * v + 3] += d * w.w;
        }
    }
    #pragma unroll
    for (int o = 0; o < 32; ++o) f1[o] = f1[o] > 0.f ? f1[o] : 0.f;

    float f2[32];
    #pragma unroll
    for (int o = 0; o < 32; ++o) f2[o] = bf2[o];
    #pragma unroll
    for (int kk = 0; kk < 32; ++kk) {
        const float4* wrow = reinterpret_cast<const float4*>(Wf2 + kk * 32);
        float d = f1[kk];
        #pragma unroll
        for (int v = 0; v < 8; ++v) {
            float4 w = wrow[v];
            f2[4 * v + 0] += d * w.x;
            f2[4 * v + 1] += d * w.y;
            f2[4 * v + 2] += d * w.z;
            f2[4 * v + 3] += d * w.w;
        }
    }
    #pragma unroll
    for (int o = 0; o < 32; ++o) f2[o] = f2[o] > 0.f ? f2[o] : 0.f;

    float q = bf3[0];
    #pragma unroll
    for (int o = 0; o < 32; o += 4) {
        float4 w = *reinterpret_cast<const float4*>(Wf3 + o);
        q += f2[o + 0] * w.x + f2[o + 1] * w.y + f2[o + 2] * w.z + f2[o + 3] * w.w;
    }

    out[pair] = q;
}

// ---------------- Fallback: known-good fused v1 (if ws too small) ------------
struct Nb1 { float s0, s1, s2; float4 r; };
__device__ __forceinline__ Nb1 load_nb1(const float* __restrict__ sg,
                                        const float* __restrict__ rr, int j) {
    Nb1 d;
    d.s0 = sg[j * 3 + 0]; d.s1 = sg[j * 3 + 1]; d.s2 = sg[j * 3 + 2];
    d.r = *reinterpret_cast<const float4*>(rr + j * 4);
    return d;
}
__global__ __launch_bounds__(256, 2) void dqn_fused_fb(
    const float* __restrict__ Sg,  const float* __restrict__ R,
    const float* __restrict__ W1,  const float* __restrict__ b1,
    const float* __restrict__ W2,  const float* __restrict__ b2,
    const float* __restrict__ Wf1, const float* __restrict__ bf1,
    const float* __restrict__ Wf2, const float* __restrict__ bf2,
    const float* __restrict__ Wf3, const float* __restrict__ bf3,
    float* __restrict__ out)
{
    const int pair = blockIdx.x * 256 + threadIdx.x;
    const float* sg = Sg + (size_t)pair * (J_ * 3);
    const float* rr = R  + (size_t)pair * (J_ * 4);
    float w1[3][10], c1[10];
    #pragma unroll
    for (int k = 0; k < 3; ++k)
        #pragma unroll
        for (int p = 0; p < 10; ++p) w1[k][p] = W1[k * 10 + p];
    #pragma unroll
    for (int p = 0; p < 10; ++p) c1[p] = b1[p];
    float M[4][10]; float Rs[4] = {0.f,0.f,0.f,0.f};
    #pragma unroll
    for (int l = 0; l < 4; ++l)
        #pragma unroll
        for (int p = 0; p < 10; ++p) M[l][p] = 0.f;
    #pragma unroll 1
    for (int j = 0; j < J_; ++j) {
        Nb1 nb = load_nb1(sg, rr, j);
        float h[10];
        #pragma unroll
        for (int p = 0; p < 10; ++p) {
            float t = c1[p] + nb.s0*w1[0][p] + nb.s1*w1[1][p] + nb.s2*w1[2][p];
            h[p] = t > 0.f ? t : 0.f;
        }
        Rs[0]+=nb.r.x; Rs[1]+=nb.r.y; Rs[2]+=nb.r.z; Rs[3]+=nb.r.w;
        #pragma unroll
        for (int p = 0; p < 10; ++p) {
            M[0][p]+=nb.r.x*h[p]; M[1][p]+=nb.r.y*h[p];
            M[2][p]+=nb.r.z*h[p]; M[3][p]+=nb.r.w*h[p];
        }
    }
    float T2[4][10];
    #pragma unroll
    for (int l = 0; l < 4; ++l)
        #pragma unroll
        for (int n = 0; n < 10; ++n) T2[l][n] = Rs[l] * b2[n];
    #pragma unroll
    for (int p = 0; p < 10; ++p) {
        #pragma unroll
        for (int l = 0; l < 4; ++l) {
            float m = M[l][p];
            #pragma unroll
            for (int n = 0; n < 10; ++n) T2[l][n] += m * W2[p * 10 + n];
        }
    }
    float D[20];
    #pragma unroll
    for (int k = 0; k < 2; ++k)
        #pragma unroll
        for (int n = 0; n < 10; ++n)
            D[k*10+n] = T2[0][k]*T2[0][n] + T2[1][k]*T2[1][n]
                      + T2[2][k]*T2[2][n] + T2[3][k]*T2[3][n];
    float f1[32];
    #pragma unroll
    for (int o = 0; o < 32; ++o) f1[o] = bf1[o];
    #pragma unroll
    for (int kk = 0; kk < 20; ++kk) {
        const float4* wrow = reinterpret_cast<const float4*>(Wf1 + kk * 32);
        float d = D[kk];
        #pragma unroll
        for (int v = 0; v < 8; ++v) {
            float4 w = wrow[v];
            f1[4*v+0]+=d*w.x; f1[4*v+1]+=d*w.y; f1[4*v+2]+=d*w.z; f1[4*v+3]+=d*w.w;
        }
    }
    #pragma unroll
    for (int o = 0; o < 32; ++o) f1[o] = f1[o] > 0.f ? f1[o] : 0.f;
    float f2[32];
    #pragma unroll
    for (int o = 0; o < 32; ++o) f2[o] = bf2[o];
    #pragma unroll
    for (int kk = 0; kk < 32; ++kk) {
        const float4* wrow = reinterpret_cast<const float4*>(Wf2 + kk * 32);
        float d = f1[kk];
        #pragma unroll
        for (int v = 0; v < 8; ++v) {
            float4 w = wrow[v];
            f2[4*v+0]+=d*w.x; f2[4*v+1]+=d*w.y; f2[4*v+2]+=d*w.z; f2[4*v+3]+=d*w.w;
        }
    }
    #pragma unroll
    for (int o = 0; o < 32; ++o) f2[o] = f2[o] > 0.f ? f2[o] : 0.f;
    float q = bf3[0];
    #pragma unroll
    for (int o = 0; o < 32; o += 4) {
        float4 w = *reinterpret_cast<const float4*>(Wf3 + o);
        q += f2[o+0]*w.x + f2[o+1]*w.y + f2[o+2]*w.z + f2[o+3]*w.w;
    }
    out[pair] = q;
}

extern "C" void kernel_launch(void* const* d_in, const int* in_sizes, int n_in,
                              void* d_out, int out_size, void* d_ws, size_t ws_size,
                              hipStream_t stream) {
    const float* Sg  = (const float*)d_in[0];
    const float* R   = (const float*)d_in[1];
    const float* W1  = (const float*)d_in[2];
    const float* b1  = (const float*)d_in[3];
    const float* W2  = (const float*)d_in[4];
    const float* b2  = (const float*)d_in[5];
    const float* Wf1 = (const float*)d_in[6];
    const float* bf1 = (const float*)d_in[7];
    const float* Wf2 = (const float*)d_in[8];
    const float* bf2 = (const float*)d_in[9];
    const float* Wf3 = (const float*)d_in[10];
    const float* bf3 = (const float*)d_in[11];
    float* out = (float*)d_out;

    if (ws_size >= D_BYTES) {
        float* Dws = (float*)d_ws;
        dqn_phase1<<<dim3(UI / PPB), dim3(THR), 0, stream>>>(
            Sg, R, W1, b1, W2, b2, Dws);
        dqn_phase2<<<dim3(UI / 256), dim3(256), 0, stream>>>(
            Dws, Wf1, bf1, Wf2, bf2, Wf3, bf3, out);
    } else {
        dqn_fused_fb<<<dim3(UI / 256), dim3(256), 0, stream>>>(
            Sg, R, W1, b1, W2, b2, Wf1, bf1, Wf2, bf2, Wf3, bf3, out);
    }
}